// Round 1
// baseline (1438.139 us; speedup 1.0000x reference)
//
#include <hip/hip_runtime.h>
#include <hip/hip_bf16.h>

#define H 320
#define W 320
#define HW (H * W)          // 102400
#define CH 64

// ---------------- bicubic x2 upsample (query 3x160x160 -> 3x320x320) --------
__device__ __forceinline__ float cubw(float t) {
    t = fabsf(t);
    if (t <= 1.f) return (1.25f * t - 2.25f) * t * t + 1.f;        // A=-0.75
    if (t < 2.f)  return -0.75f * (((t - 5.f) * t + 8.f) * t - 4.f);
    return 0.f;
}

__global__ __launch_bounds__(256) void bicubic_k(const float* __restrict__ q,
                                                 float* __restrict__ outp) {
    int idx = blockIdx.x * 256 + threadIdx.x;
    if (idx >= 3 * HW) return;
    int c = idx / HW;
    int r = idx - c * HW;
    int oy = r / W, ox = r - (r / W) * W;
    float sy = oy * 0.5f - 0.25f;
    float sx = ox * 0.5f - 0.25f;
    int iy0 = (int)floorf(sy);
    int ix0 = (int)floorf(sx);
    float wy[4], wx[4];
    int tyi[4], txi[4];
#pragma unroll
    for (int a = 0; a < 4; a++) {
        int ty = iy0 - 1 + a;
        wy[a] = cubw(sy - (float)ty);
        tyi[a] = min(max(ty, 0), 159);
        int tx = ix0 - 1 + a;
        wx[a] = cubw(sx - (float)tx);
        txi[a] = min(max(tx, 0), 159);
    }
    const float* ip = q + c * (160 * 160);
    float o = 0.f;
#pragma unroll
    for (int b = 0; b < 4; b++) {
        float s = 0.f;
#pragma unroll
        for (int a = 0; a < 4; a++) s += wy[a] * ip[tyi[a] * 160 + txi[b]];
        o += wx[b] * s;
    }
    outp[idx] = o;
}

// ---------------- direct conv, COUT=32, LDS-tiled ---------------------------
// ACT: 0 = relu, 1 = leaky-relu(0.2). RES: add residual before activation.
template <int KS, int CIN, int ACT, bool RES>
__global__ __launch_bounds__(256) void conv_k(const float* __restrict__ in,
                                              const float* __restrict__ wgt,
                                              const float* __restrict__ bias,
                                              const float* __restrict__ res,
                                              float* __restrict__ out) {
    constexpr int PAD = KS / 2;
    constexpr int TW = 16 + KS - 1;          // 18 or 20
    constexpr int KS2 = KS * KS;             // 9 or 25
    constexpr int WSTR = (KS2 + 3) & ~3;     // 12 or 28 (16B-aligned rows)
    __shared__ float tile[TW * TW];
    __shared__ float wl[32 * WSTR];
    const int tid = threadIdx.x;
    const int tx = tid & 15, ty = tid >> 4;
    const int bx = blockIdx.x % 20, by = blockIdx.x / 20;
    const int ox = bx * 16 + tx, oy = by * 16 + ty;

    float acc[32];
#pragma unroll
    for (int i = 0; i < 32; i++) acc[i] = 0.f;

    for (int ic = 0; ic < CIN; ++ic) {
        __syncthreads();
        const float* ip = in + ic * HW;
        for (int idx = tid; idx < TW * TW; idx += 256) {
            int iy = by * 16 - PAD + idx / TW;
            int ix = bx * 16 - PAD + idx % TW;
            float v = 0.f;
            if (iy >= 0 && iy < H && ix >= 0 && ix < W) v = ip[iy * W + ix];
            tile[idx] = v;
        }
        for (int idx = tid; idx < 32 * KS2; idx += 256) {
            int oc = idx / KS2, t = idx - oc * KS2;
            wl[oc * WSTR + t] = wgt[(oc * CIN + ic) * KS2 + t];
        }
        __syncthreads();
        float iv[KS2];
#pragma unroll
        for (int t = 0; t < KS2; t++)
            iv[t] = tile[(ty + t / KS) * TW + tx + t % KS];
#pragma unroll
        for (int oc = 0; oc < 32; ++oc) {
            float s = 0.f;
#pragma unroll
            for (int t = 0; t < KS2; t++) s += iv[t] * wl[oc * WSTR + t];
            acc[oc] += s;
        }
    }

    const int p = oy * W + ox;
#pragma unroll
    for (int oc = 0; oc < 32; ++oc) {
        float v = acc[oc] + bias[oc];
        if constexpr (RES) v += res[oc * HW + p];
        if constexpr (ACT == 0) v = fmaxf(v, 0.f);
        else                    v = (v > 0.f) ? v : 0.2f * v;
        out[oc * HW + p] = v;
    }
}

// ---------------- 1x1 conv 32->3, +1, clip ----------------------------------
__global__ __launch_bounds__(256) void affine_k(const float* __restrict__ hid,
                                                const float* __restrict__ w,
                                                const float* __restrict__ b,
                                                float* __restrict__ outp) {
    int p = blockIdx.x * 256 + threadIdx.x;
    if (p >= HW) return;
    float a0 = 0.f, a1 = 0.f, a2 = 0.f;
    for (int c = 0; c < 32; c++) {
        float h = hid[c * HW + p];
        a0 += h * w[c];
        a1 += h * w[32 + c];
        a2 += h * w[64 + c];
    }
    a0 = fminf(fmaxf(a0 + b[0] + 1.f, -3.f), 3.f);
    a1 = fminf(fmaxf(a1 + b[1] + 1.f, -3.f), 3.f);
    a2 = fminf(fmaxf(a2 + b[2] + 1.f, -3.f), 3.f);
    outp[p] = a0;
    outp[HW + p] = a1;
    outp[2 * HW + p] = a2;
}

// ---------------- deformable 2x2 bilinear sampling --------------------------
__device__ __forceinline__ int reflmap(int q) {
    // q in [0,321] indexes reflect-padded xp; map to source row/col in [0,319]
    int s = q - 1;
    if (s < 0) s = -s;
    else if (s > 319) s = 638 - s;
    return s;
}

__global__ __launch_bounds__(256) void sample_k(const float* __restrict__ x,
                                                const float* __restrict__ aff,
                                                float* __restrict__ outp) {
    int idx = blockIdx.x * 256 + threadIdx.x;   // over 640*640 output pixels
    if (idx >= 640 * 640) return;
    int ow = idx % 640, oh = idx / 640;
    int w = ow >> 1, h = oh >> 1;
    int ky = ow & 1, kx = oh & 1;
    int p = h * W + w;
    float s_x = aff[p];
    float s_y = aff[HW + p];
    float th = (aff[2 * HW + p] - 1.f) * 1.0472f;
    float pnx = kx ? 0.5f : -0.5f;
    float pny = ky ? 0.5f : -0.5f;
    float px = pnx * s_x, py = pny * s_y;
    float st, ct;
    __sincosf(th, &st, &ct);
    float rx = px * ct - py * st;
    float ry = px * st + py * ct;
    float p_x = rx + 0.5f + (float)(h + 1);
    float p_y = ry + 0.5f + (float)(w + 1);
    float ltx = floorf(p_x), lty = floorf(p_y);
    float rbx = ltx + 1.f, rby = lty + 1.f;
    float ltxc = fminf(fmaxf(ltx, 0.f), 321.f);
    float ltyc = fminf(fmaxf(lty, 0.f), 321.f);
    float rbxc = fminf(fmaxf(rbx, 0.f), 321.f);
    float rbyc = fminf(fmaxf(rby, 0.f), 321.f);
    p_x = fminf(fmaxf(p_x, 0.f), 321.f);
    p_y = fminf(fmaxf(p_y, 0.f), 321.f);
    float gx0 = 1.f + ltxc - p_x;
    float gx1 = 1.f - (rbxc - p_x);
    float gy0 = 1.f + ltyc - p_y;
    float gy1 = 1.f - (rbyc - p_y);
    float g_lt = gx0 * gy0, g_rb = gx1 * gy1, g_lb = gx0 * gy1, g_rt = gx1 * gy0;
    int ix0 = reflmap((int)ltxc), ix1 = reflmap((int)rbxc);
    int iy0 = reflmap((int)ltyc), iy1 = reflmap((int)rbyc);
    int o00 = ix0 * W + iy0;
    int o11 = ix1 * W + iy1;
    int o01 = ix0 * W + iy1;
    int o10 = ix1 * W + iy0;
    int obase = oh * 640 + ow;
    for (int c = 0; c < CH; c++) {
        const float* xc = x + c * HW;
        float v = g_lt * xc[o00] + g_rb * xc[o11] + g_lb * xc[o01] + g_rt * xc[o10];
        outp[c * (640 * 640) + obase] = v;
    }
}

// ---------------- launch ----------------------------------------------------
extern "C" void kernel_launch(void* const* d_in, const int* in_sizes, int n_in,
                              void* d_out, int out_size, void* d_ws, size_t ws_size,
                              hipStream_t stream) {
    const float* x       = (const float*)d_in[0];
    const float* query   = (const float*)d_in[1];
    const float* ref     = (const float*)d_in[2];
    const float* conv1_w = (const float*)d_in[3];
    const float* conv1_b = (const float*)d_in[4];
    const float* r1_w1   = (const float*)d_in[5];
    const float* r1_b1   = (const float*)d_in[6];
    const float* r1_w2   = (const float*)d_in[7];
    const float* r1_b2   = (const float*)d_in[8];
    const float* p1_w    = (const float*)d_in[9];
    const float* p1_b    = (const float*)d_in[10];
    const float* pr_w1   = (const float*)d_in[11];
    const float* pr_b1   = (const float*)d_in[12];
    const float* pr_w2   = (const float*)d_in[13];
    const float* pr_b2   = (const float*)d_in[14];
    const float* p2_w    = (const float*)d_in[15];
    const float* p2_b    = (const float*)d_in[16];

    float* outp = (float*)d_out;
    float* ws = (float*)d_ws;

    // small scratch in d_ws (2.4 MB), big intermediates inside d_out
    // (d_out = 26.21M floats; scratch usage 16.38M floats, all dead before
    //  sample_k rewrites every element of d_out).
    float* qup    = ws;                 // 3*HW
    float* affine = ws + 3 * HW;        // 3*HW
    float* feat   = outp;               // 64*HW   (rf ch 0..31, qf ch 32..63)
    float* B      = outp + 64 * HW;     // 32*HW
    float* C      = outp + 96 * HW;     // 32*HW
    float* D      = outp + 128 * HW;    // 32*HW

    bicubic_k<<<1200, 256, 0, stream>>>(query, qup);

    // qf head
    conv_k<5, 3, 1, false><<<400, 256, 0, stream>>>(qup, conv1_w, conv1_b, nullptr, B);
    conv_k<3, 32, 0, false><<<400, 256, 0, stream>>>(B, r1_w1, r1_b1, nullptr, C);
    conv_k<3, 32, 1, true><<<400, 256, 0, stream>>>(C, r1_w2, r1_b2, B, feat + 32 * HW);

    // rf head
    conv_k<5, 3, 1, false><<<400, 256, 0, stream>>>(ref, conv1_w, conv1_b, nullptr, B);
    conv_k<3, 32, 0, false><<<400, 256, 0, stream>>>(B, r1_w1, r1_b1, nullptr, C);
    conv_k<3, 32, 1, true><<<400, 256, 0, stream>>>(C, r1_w2, r1_b2, B, feat);

    // fusion head
    conv_k<5, 64, 1, false><<<400, 256, 0, stream>>>(feat, p1_w, p1_b, nullptr, B);
    conv_k<3, 32, 0, false><<<400, 256, 0, stream>>>(B, pr_w1, pr_b1, nullptr, C);
    conv_k<3, 32, 1, true><<<400, 256, 0, stream>>>(C, pr_w2, pr_b2, B, D);

    affine_k<<<400, 256, 0, stream>>>(D, p2_w, p2_b, affine);

    sample_k<<<1600, 256, 0, stream>>>(x, affine, outp);
}